// Round 3
// baseline (6425.756 us; speedup 1.0000x reference)
//
#include <hip/hip_runtime.h>
#include <hip/hip_bf16.h>

#define Bn   1024
#define Tn   730
#define INn  64
#define Hn   512
#define Kn   576      // INn + Hn
#define G4n  2048     // 4*Hn

typedef __bf16 bf16x8 __attribute__((ext_vector_type(8)));
typedef float  f32x4  __attribute__((ext_vector_type(4)));
typedef float  f32x2  __attribute__((ext_vector_type(2)));

// z exchange per half: [32 rows][2 khalf][128 gatecols], row stride ZROW floats.
// ZROW=268: 268%32==12 -> scatter lanes collide only 2-way (free, m136);
// f32x2 gather spreads over all bank-pairs (conflict-free, verified arithmetic).
#define ZROW   268
#define A_HALF 2304                 // bf16x8 slots per half A-tile (36 slots * 64 lanes)
#define ZP_OFF 73728                // byte offset of z region, half P
#define ZQ_OFF (73728 + 34304)      // half Q (32*268*4 = 34304 B per half)

// ---------------- weight pre-pack: Wc[row][k] bf16, row = gate*512+j, k over [x|h] ----------
__global__ void convert_weights(const float* __restrict__ Wih,
                                const float* __restrict__ Whh,
                                __bf16* __restrict__ Wc) {
    int idx = blockIdx.x * 256 + threadIdx.x;
    if (idx >= G4n * Kn) return;
    int row = idx / Kn;
    int k   = idx - row * Kn;
    float v = (k < INn) ? Wih[row * INn + k] : Whh[row * Hn + (k - INn)];
    Wc[idx] = (__bf16)v;
}

__device__ __forceinline__ float sigf(float x)   { return 1.0f / (1.0f + __expf(-x)); }
__device__ __forceinline__ float tanhf_f(float x){ return 2.0f * sigf(2.0f * x) - 1.0f; }

// ---------------- persistent LSTM scan ----------------
// 256 blocks x 512 threads (8 waves), 1 block/CU. Block = (mi: 64 batch rows) x (nj: 32 h-cols).
// The 64 rows split into two INDEPENDENT 32-row sub-chains P/Q with separate barrier
// groups; per iter the block runs P-segment then Q-segment, so each half's barrier
// propagation + IC latency elapses during the other half's compute (latency hiding).
// Wave role (2x2x2): ch = gate-pair (64 gatecols), kh = K-half (288), rh = row-half (16 rows).
// Weights: 36 x bf16x8 = 144 VGPR/lane, shared by both halves. A-frag LDS reads:
// 9 b128/wave/half -> cross-wave multiplicity 2 (was 4 in round-2).
// COHERENCE (proven round-0/2 scheme): all cross-block data via RELAXED agent-scope
// atomics (sc1 write-through/bypass to IC); __syncthreads drains vmcnt(0) before the
// barrier counter bump, so h stores are IC-visible before the count.
__global__ __launch_bounds__(512, 2) void lstm_persist(
    const float* __restrict__ xd,     // [B,T,IN]
    const float* __restrict__ bias,   // [4H]
    const __bf16* __restrict__ Wc,    // [4H][Kn]
    __bf16* __restrict__ h0,          // [B,H] buffer A (final h lands here)
    __bf16* __restrict__ h1,          // [B,H] buffer B
    unsigned int* __restrict__ bar)   // 32 groups x 32 uints (128B stride)
{
    // LDS: A-tiles 2 x 36864 B (fragment order) + z 2 x 34304 B = 142336 B
    __shared__ __align__(16) char smem[142336];
    bf16x8* aTile = (bf16x8*)smem;
    float*  zB0   = (float*)(smem + ZP_OFF);
    float*  zB1   = (float*)(smem + ZQ_OFF);

    const int blk  = blockIdx.x;
    const int xcd  = blk & 7;
    const int slot = blk >> 3;
    const int mi   = xcd * 2 + (slot & 1);
    const int nj   = slot >> 1;
    const int m0   = mi << 6;
    const int j0   = nj << 5;

    const int tid  = threadIdx.x;              // 0..511
    const int wave = tid >> 6;                 // 0..7
    const int lane = tid & 63;
    const int q    = lane >> 4;
    const int l16  = lane & 15;

    const int ch = wave & 1;                   // gate-pair: gates {2ch, 2ch+1}
    const int kh = (wave >> 1) & 1;            // K half: kb 9*kh .. 9*kh+8
    const int rh = wave >> 2;                  // row half within 32 rows

    // ---- resident weights: 9 kb x 4 colgroups (gate = 2ch+(cg>>1), jc = (cg&1)*16+l16) ----
    bf16x8 wreg[9][4];
    float  bini[4];
    #pragma unroll
    for (int cg = 0; cg < 4; ++cg) {
        const int gate = 2 * ch + (cg >> 1);
        const int jc   = (cg & 1) * 16 + l16;
        #pragma unroll
        for (int kb = 0; kb < 9; ++kb)
            wreg[kb][cg] = *(const bf16x8*)(Wc + (size_t)(gate * Hn + j0 + jc) * Kn
                                               + (kh * 9 + kb) * 32 + q * 8);
        bini[cg] = kh ? 0.f : bias[gate * Hn + j0 + jc];   // bias folded into kh=0 acc init
    }

    // ---- pointwise ownership (per half): thread -> (row pr of 32, 2 cols jc2,jc2+1) ----
    const int pr  = tid >> 4;                  // 0..31
    const int jc2 = (tid & 15) << 1;           // 0..30
    float creg[2][2] = {{0.f, 0.f}, {0.f, 0.f}};

    // ---- x staging role: thread stages 1 frag of its half (half = tid>>8) ----
    const int myh    = tid >> 8;               // which half this thread stages x for
    const int xt     = tid & 255;
    const int xrg    = (xt >> 7) & 1;          // slot 0..3 -> rg, kb
    const int xkb    = (xt >> 6) & 1;
    const int xlane  = xt & 63;
    const int xq     = xlane >> 4;
    const int xl16   = xlane & 15;
    const float* xrb = xd + (size_t)(m0 + myh * 32 + xrg * 16 + xl16) * (Tn * INn)
                          + xkb * 32 + xq * 8;
    const int xslot  = myh * A_HALF + (xrg * 18 + xkb) * 64 + xlane;

    unsigned int* cntH[2] = { bar + ((mi * 2 + 0) << 5), bar + ((mi * 2 + 1) << 5) };
    bool dead = false;

    // ---- prologue: stage x(t=0) for both halves ----
    {
        f32x4 lo = *(const f32x4*)xrb;
        f32x4 hi = *(const f32x4*)(xrb + 4);
        bf16x8 v;
        v[0] = (__bf16)lo[0]; v[1] = (__bf16)lo[1]; v[2] = (__bf16)lo[2]; v[3] = (__bf16)lo[3];
        v[4] = (__bf16)hi[0]; v[5] = (__bf16)hi[1]; v[6] = (__bf16)hi[2]; v[7] = (__bf16)hi[3];
        aTile[xslot] = v;
    }

    for (int t = 0; t < Tn; ++t) {
        const __bf16* hread  = (t & 1) ? h1 : h0;
        __bf16*       hwrite = (t & 1) ? h0 : h1;

        #pragma unroll
        for (int half = 0; half < 2; ++half) {
            float* z = half ? zB1 : zB0;

            // ---- (a) wait: this half's h(t) complete across the 16-block group ----
            if (tid == 0 && t > 0 && !dead) {
                const unsigned int target = 16u * (unsigned int)t;
                int spins = 0;
                while (__hip_atomic_load(cntH[half], __ATOMIC_RELAXED, __HIP_MEMORY_SCOPE_AGENT) < target) {
                    __builtin_amdgcn_s_sleep(2);
                    if (++spins > 300000) { dead = true; break; }  // hang -> fast wrong-answer
                }
            }
            __syncthreads();   // (b) release wait; also fences LDS reuse

            // ---- (c) h(t) -> regs (8 u64 loads in flight); issue x(t+1) loads ----
            unsigned long long hu[4][2];
            #pragma unroll
            for (int rg = 0; rg < 2; ++rg) {
                #pragma unroll
                for (int j = 0; j < 2; ++j) {
                    const unsigned long long* hp = (const unsigned long long*)
                        (hread + (size_t)(m0 + half * 32 + rg * 16 + l16) * Hn
                               + (wave + 8 * j) * 32 + q * 8);
                    hu[rg * 2 + j][0] = __hip_atomic_load(hp,     __ATOMIC_RELAXED, __HIP_MEMORY_SCOPE_AGENT);
                    hu[rg * 2 + j][1] = __hip_atomic_load(hp + 1, __ATOMIC_RELAXED, __HIP_MEMORY_SCOPE_AGENT);
                }
            }
            f32x4 xlo, xhi;
            const bool mx = (myh == half) && (t + 1 < Tn);
            if (mx) {
                const float* xp = xrb + (size_t)(t + 1) * INn;
                xlo = *(const f32x4*)xp;
                xhi = *(const f32x4*)(xp + 4);
            }
            #pragma unroll
            for (int rg = 0; rg < 2; ++rg) {
                #pragma unroll
                for (int j = 0; j < 2; ++j) {
                    union { unsigned long long u[2]; bf16x8 v; } cv;
                    cv.u[0] = hu[rg * 2 + j][0];
                    cv.u[1] = hu[rg * 2 + j][1];
                    aTile[half * A_HALF + (rg * 18 + 2 + wave + 8 * j) * 64 + lane] = cv.v;
                }
            }
            __syncthreads();   // (d)

            // ---- (e) MFMA: wave's (rh rows x 64 gatecols x K-half); A from LDS ----
            f32x4 acc[4];
            #pragma unroll
            for (int cg = 0; cg < 4; ++cg)
                acc[cg] = (f32x4){bini[cg], bini[cg], bini[cg], bini[cg]};
            #pragma unroll
            for (int kb = 0; kb < 9; ++kb) {
                const bf16x8 af = aTile[half * A_HALF + (rh * 18 + kh * 9 + kb) * 64 + lane];
                #pragma unroll
                for (int cg = 0; cg < 4; ++cg)
                    acc[cg] = __builtin_amdgcn_mfma_f32_16x16x32_bf16(af, wreg[kb][cg], acc[cg], 0, 0, 0);
            }
            // z scatter: row = rh*16 + q*4 + e, section = kh, gidx = ch*64 + cg*16 + l16
            #pragma unroll
            for (int cg = 0; cg < 4; ++cg) {
                #pragma unroll
                for (int e = 0; e < 4; ++e)
                    z[(rh * 16 + q * 4 + e) * ZROW + kh * 128 + ch * 64 + cg * 16 + l16]
                        = acc[cg][e];
            }
            __syncthreads();   // (f)

            // ---- (g) pointwise: gather 4 gates x 2 khalf, activate, store h(t+1) ----
            float zg[4][2];
            #pragma unroll
            for (int g = 0; g < 4; ++g) {
                f32x2 v0 = *(const f32x2*)&z[pr * ZROW +       g * 32 + jc2];
                f32x2 v1 = *(const f32x2*)&z[pr * ZROW + 128 + g * 32 + jc2];
                zg[g][0] = v0[0] + v1[0];
                zg[g][1] = v0[1] + v1[1];
            }
            union { unsigned int u; __bf16 h[2]; } pk;
            #pragma unroll
            for (int cc = 0; cc < 2; ++cc) {
                const float cn = sigf(zg[1][cc]) * creg[half][cc]
                               + sigf(zg[0][cc]) * tanhf_f(zg[2][cc]);
                creg[half][cc] = cn;
                pk.h[cc] = (__bf16)(sigf(zg[3][cc]) * tanhf_f(cn));
            }
            __hip_atomic_store((unsigned int*)(hwrite + (size_t)(m0 + half * 32 + pr) * Hn + j0 + jc2),
                               pk.u, __ATOMIC_RELAXED, __HIP_MEMORY_SCOPE_AGENT);

            // finish x(t+1) staging (loads issued at (c), latency hidden by MFMA+gates)
            if (mx) {
                bf16x8 v;
                v[0] = (__bf16)xlo[0]; v[1] = (__bf16)xlo[1]; v[2] = (__bf16)xlo[2]; v[3] = (__bf16)xlo[3];
                v[4] = (__bf16)xhi[0]; v[5] = (__bf16)xhi[1]; v[6] = (__bf16)xhi[2]; v[7] = (__bf16)xhi[3];
                aTile[xslot] = v;
            }

            // ---- (h) arrive: drain h stores (vmcnt0 via syncthreads), bump counter ----
            __syncthreads();
            if (tid == 0)
                __hip_atomic_fetch_add(cntH[half], 1u, __ATOMIC_RELAXED, __HIP_MEMORY_SCOPE_AGENT);
        }
    }
}

// ---------------- head: out[b] = relu(dot(h_T[b], Wl) + bl) ----------------
__global__ void head_kernel(const __bf16* __restrict__ h, const float* __restrict__ Wl,
                            const float* __restrict__ bl, float* __restrict__ out) {
    const int b = blockIdx.x;
    const int lane = threadIdx.x;  // 64 threads
    const __bf16* hp = h + (size_t)b * Hn;
    float s = 0.f;
    #pragma unroll
    for (int j = lane; j < Hn; j += 64) s += (float)hp[j] * Wl[j];
    #pragma unroll
    for (int off = 32; off > 0; off >>= 1) s += __shfl_down(s, off, 64);
    if (lane == 0) out[b] = fmaxf(s + bl[0], 0.0f);
}

extern "C" void kernel_launch(void* const* d_in, const int* in_sizes, int n_in,
                              void* d_out, int out_size, void* d_ws, size_t ws_size,
                              hipStream_t stream) {
    const float* xd  = (const float*)d_in[0];
    const float* Wih = (const float*)d_in[1];
    const float* Whh = (const float*)d_in[2];
    const float* b   = (const float*)d_in[3];
    const float* Wl  = (const float*)d_in[4];
    const float* bl  = (const float*)d_in[5];
    float* out = (float*)d_out;

    // ws layout:
    //   Wc  bf16 [2048][576] : 2,359,296 B
    //   h0  bf16 [1024][512] : 1,048,576 B
    //   h1  bf16 [1024][512] : 1,048,576 B
    //   bar u32  [32][32]    : 4,096 B
    char* ws = (char*)d_ws;
    __bf16* Wc = (__bf16*)ws;
    __bf16* h0 = (__bf16*)(ws + 2359296);
    __bf16* h1 = (__bf16*)(ws + 2359296 + 1048576);
    unsigned int* bar = (unsigned int*)(ws + 2359296 + 2 * 1048576);

    hipMemsetAsync(h0, 0, 1048576, stream);   // t=0 reads h0 as zeros
    hipMemsetAsync(bar, 0, 4096, stream);     // monotonic barrier counters (32 groups)

    const int total = G4n * Kn;
    convert_weights<<<(total + 255) / 256, 256, 0, stream>>>(Wih, Whh, Wc);

    lstm_persist<<<256, 512, 0, stream>>>(xd, b, Wc, h0, h1, bar);

    // t=729 (odd) writes h0 -> final hidden state is in h0
    head_kernel<<<Bn, 64, 0, stream>>>(h0, Wl, bl, out);
}

// Round 4
// 3630.921 us; speedup vs baseline: 1.7697x; 1.7697x over previous
//
#include <hip/hip_runtime.h>
#include <hip/hip_bf16.h>

#define Bn   1024
#define Tn   730
#define INn  64
#define Hn   512
#define Kn   576      // INn + Hn
#define G4n  2048     // 4*Hn

typedef __bf16 bf16x8 __attribute__((ext_vector_type(8)));
typedef float  f32x4  __attribute__((ext_vector_type(4)));

// Block tile: 32 batch rows x 64 h-cols (256 gate-cols), K full 576.
// A-tile: 32 x 576 bf16 in MFMA-fragment order = 36864 B.
// z exchange: [32 rows][2 khalf][256 gatecols], row stride ZROW=524 floats
// (524 mod 32 = 12 -> scatter 2-way-free (m136: free), f32x4 gather uniform; the
// 268-residue family measured ZERO conflicts in round-3).
#define ZROW   524
#define Z_OFF  36864

// ---------------- weight pre-pack: Wc[row][k] bf16, row = gate*512+j, k over [x|h] ----------
__global__ void convert_weights(const float* __restrict__ Wih,
                                const float* __restrict__ Whh,
                                __bf16* __restrict__ Wc) {
    int idx = blockIdx.x * 256 + threadIdx.x;
    if (idx >= G4n * Kn) return;
    int row = idx / Kn;
    int k   = idx - row * Kn;
    float v = (k < INn) ? Wih[row * INn + k] : Whh[row * Hn + (k - INn)];
    Wc[idx] = (__bf16)v;
}

// fast sigmoid: v_exp + single v_rcp (error ~1ulp << bf16 h-quantization)
__device__ __forceinline__ float sigf(float x)   { return __builtin_amdgcn_rcpf(1.0f + __expf(-x)); }
__device__ __forceinline__ float tanhf_f(float x){ return 2.0f * sigf(2.0f * x) - 1.0f; }

// ---------------- persistent LSTM scan ----------------
// 256 blocks x 512 threads (8 waves), 1 block/CU. Block = (rg_i: 32 batch rows) x (cb: 64 h-cols).
// vs round-2 (64x32): h-exchange volume per block HALVED (32KB), barrier group 16 -> 8
// arrivals, A-tile LDS reads halved — same 4-syncs/step single-chain schedule (round-3
// showed extra phase segmentation costs more than LDS-port savings).
// Wave role: kh = wave&1 (K-half 288), cq = wave>>1 (64 of 256 gate-cols).
// Weights: 36 x bf16x8 = 144 VGPR/lane. Per wave: 18 A-frag b128 reads, 72 MFMA.
// COHERENCE (proven round-0/2 scheme): all cross-block data via RELAXED agent-scope
// atomics (write-through/bypass to IC); __syncthreads drains vmcnt(0) before the
// barrier counter bump, so h stores are IC-visible before the count.
__global__ __launch_bounds__(512, 1) void lstm_persist(
    const float* __restrict__ xd,     // [B,T,IN]
    const float* __restrict__ bias,   // [4H]
    const __bf16* __restrict__ Wc,    // [4H][Kn]
    __bf16* __restrict__ h0,          // [B,H] buffer A (final h lands here)
    __bf16* __restrict__ h1,          // [B,H] buffer B
    unsigned int* __restrict__ bar)   // 32 groups x 32 uints (128B stride)
{
    // LDS: A-tile 36864 B + z 32*524*4 = 67072 B -> 103936 B (1 block/CU)
    __shared__ __align__(16) char smem[Z_OFF + ZROW * 32 * 4];
    bf16x8* aTile = (bf16x8*)smem;
    float*  zT    = (float*)(smem + Z_OFF);

    const int blk  = blockIdx.x;
    // group (rg_i) pinned to one XCD-slot (blk&7); 8 col-blocks per group
    const int rg_i = (blk & 7) * 4 + ((blk >> 3) & 3);   // 0..31 row-group
    const int cb   = blk >> 5;                           // 0..7  col-block
    const int m0   = rg_i << 5;
    const int j0   = cb << 6;

    const int tid  = threadIdx.x;              // 0..511
    const int wave = tid >> 6;                 // 0..7
    const int lane = tid & 63;
    const int q    = lane >> 4;
    const int l16  = lane & 15;

    const int kh = wave & 1;                   // K half: kb 9*kh .. 9*kh+8
    const int cq = wave >> 1;                  // gate-col quarter (64 of 256)

    // ---- resident weights: 9 kb x 4 colgroups; gcg = cq*4+cg -> gate = gcg>>2, jsub = gcg&3 ----
    bf16x8 wreg[9][4];
    float  bini[4];
    #pragma unroll
    for (int cg = 0; cg < 4; ++cg) {
        const int gcg  = cq * 4 + cg;
        const int gate = gcg >> 2;
        const int col  = j0 + (gcg & 3) * 16 + l16;
        #pragma unroll
        for (int kb = 0; kb < 9; ++kb)
            wreg[kb][cg] = *(const bf16x8*)(Wc + (size_t)(gate * Hn + col) * Kn
                                               + (kh * 9 + kb) * 32 + q * 8);
        bini[cg] = kh ? 0.f : bias[gate * Hn + col];   // bias folded into kh=0 acc init
    }

    // ---- pointwise ownership: thread -> (row r of 32, 4 consecutive cols) ----
    const int r  = tid >> 4;                   // 0..31
    const int c4 = (tid & 15) << 2;            // 0..60
    float creg[4] = {0.f, 0.f, 0.f, 0.f};

    // ---- h staging: wave stages frags hf = wave*4 + i (rg = hf>>4, kbh = hf&15) ----
    // src col = kbh*32 + q*8 ; slot = (rg*18 + kbh + 2)*64 + lane
    // ---- x staging: threads 0..255, frag f = tid>>6 (rg = f>>1, kb = f&1) ----
    const int xt    = tid & 255;
    const int xrg   = (xt >> 7) & 1;
    const int xkb   = (xt >> 6) & 1;
    const int xlane = xt & 63;
    const int xq    = xlane >> 4;
    const int xl16  = xlane & 15;
    const float* xrb = xd + (size_t)(m0 + xrg * 16 + xl16) * (Tn * INn) + xkb * 32 + xq * 8;
    const int xslot  = (xrg * 18 + xkb) * 64 + xlane;
    const bool xown  = (tid < 256);

    unsigned int* cnt = bar + (rg_i << 5);     // one 128B line per group
    bool dead = false;

    // ---- prologue: stage x(t=0) ----
    if (xown) {
        f32x4 lo = *(const f32x4*)xrb;
        f32x4 hi = *(const f32x4*)(xrb + 4);
        bf16x8 v;
        v[0] = (__bf16)lo[0]; v[1] = (__bf16)lo[1]; v[2] = (__bf16)lo[2]; v[3] = (__bf16)lo[3];
        v[4] = (__bf16)hi[0]; v[5] = (__bf16)hi[1]; v[6] = (__bf16)hi[2]; v[7] = (__bf16)hi[3];
        aTile[xslot] = v;
    }

    for (int t = 0; t < Tn; ++t) {
        const __bf16* hread  = (t & 1) ? h1 : h0;
        __bf16*       hwrite = (t & 1) ? h0 : h1;

        // ---- phase 1: h -> regs (8 u64 loads all in flight), then -> LDS ----
        unsigned long long hu[4][2];
        #pragma unroll
        for (int i = 0; i < 4; ++i) {
            const int hf  = wave * 4 + i;
            const int rg  = hf >> 4;
            const int kbh = hf & 15;
            const unsigned long long* hp = (const unsigned long long*)
                (hread + (size_t)(m0 + rg * 16 + l16) * Hn + kbh * 32 + q * 8);
            hu[i][0] = __hip_atomic_load(hp,     __ATOMIC_RELAXED, __HIP_MEMORY_SCOPE_AGENT);
            hu[i][1] = __hip_atomic_load(hp + 1, __ATOMIC_RELAXED, __HIP_MEMORY_SCOPE_AGENT);
        }
        #pragma unroll
        for (int i = 0; i < 4; ++i) {
            const int hf  = wave * 4 + i;
            const int rg  = hf >> 4;
            const int kbh = hf & 15;
            union { unsigned long long u[2]; bf16x8 v; } cv;
            cv.u[0] = hu[i][0]; cv.u[1] = hu[i][1];
            aTile[(rg * 18 + kbh + 2) * 64 + lane] = cv.v;
        }
        __syncthreads();

        // ---- phase 2: MFMA: wave's (32 rows x 64 gatecols x K-half); A from LDS ----
        f32x4 acc[2][4];
        #pragma unroll
        for (int rg = 0; rg < 2; ++rg)
            #pragma unroll
            for (int cg = 0; cg < 4; ++cg)
                acc[rg][cg] = (f32x4){bini[cg], bini[cg], bini[cg], bini[cg]};
        #pragma unroll
        for (int kb = 0; kb < 9; ++kb) {
            const bf16x8 af0 = aTile[(0 * 18 + kh * 9 + kb) * 64 + lane];
            const bf16x8 af1 = aTile[(1 * 18 + kh * 9 + kb) * 64 + lane];
            #pragma unroll
            for (int cg = 0; cg < 4; ++cg) {
                acc[0][cg] = __builtin_amdgcn_mfma_f32_16x16x32_bf16(af0, wreg[kb][cg], acc[0][cg], 0, 0, 0);
                acc[1][cg] = __builtin_amdgcn_mfma_f32_16x16x32_bf16(af1, wreg[kb][cg], acc[1][cg], 0, 0, 0);
            }
        }
        // z scatter: row = rg*16 + q*4 + e; linear gatecol = (cq*4+cg)*16 + l16
        #pragma unroll
        for (int rg = 0; rg < 2; ++rg)
            #pragma unroll
            for (int cg = 0; cg < 4; ++cg)
                #pragma unroll
                for (int e = 0; e < 4; ++e)
                    zT[(rg * 16 + q * 4 + e) * ZROW + kh * 256 + (cq * 4 + cg) * 16 + l16]
                        = acc[rg][cg][e];
        __syncthreads();

        // ---- phase 3: issue x(t+1) loads; pointwise under their latency ----
        f32x4 xlo, xhi;
        const bool mx = xown && (t + 1 < Tn);
        if (mx) {
            const float* xp = xrb + (size_t)(t + 1) * INn;
            xlo = *(const f32x4*)xp;
            xhi = *(const f32x4*)(xp + 4);
        }

        // gate pointwise: f32x4 gather of both K-halves, sum, activate
        float zg[4][4];
        #pragma unroll
        for (int g = 0; g < 4; ++g) {
            f32x4 v0 = *(const f32x4*)&zT[r * ZROW +       g * 64 + c4];
            f32x4 v1 = *(const f32x4*)&zT[r * ZROW + 256 + g * 64 + c4];
            f32x4 s  = v0 + v1;
            zg[g][0] = s[0]; zg[g][1] = s[1]; zg[g][2] = s[2]; zg[g][3] = s[3];
        }
        union { unsigned long long u; __bf16 h[4]; } pk;
        #pragma unroll
        for (int cc = 0; cc < 4; ++cc) {
            const float cn = sigf(zg[1][cc]) * creg[cc]
                           + sigf(zg[0][cc]) * tanhf_f(zg[2][cc]);
            creg[cc] = cn;
            pk.h[cc] = (__bf16)(sigf(zg[3][cc]) * tanhf_f(cn));
        }
        __hip_atomic_store((unsigned long long*)(hwrite + (size_t)(m0 + r) * Hn + j0 + c4),
                           pk.u, __ATOMIC_RELAXED, __HIP_MEMORY_SCOPE_AGENT);

        // finish x(t+1) staging (loads have had the gate math to land)
        if (mx) {
            bf16x8 v;
            v[0] = (__bf16)xlo[0]; v[1] = (__bf16)xlo[1]; v[2] = (__bf16)xlo[2]; v[3] = (__bf16)xlo[3];
            v[4] = (__bf16)xhi[0]; v[5] = (__bf16)xhi[1]; v[6] = (__bf16)xhi[2]; v[7] = (__bf16)xhi[3];
            aTile[xslot] = v;
        }

        // ---- phase 4: group barrier (8 blocks sharing rg_i), relaxed atomics only ----
        __syncthreads();   // drains vmcnt(0): all write-through h stores at IC
        if (tid == 0) {
            __hip_atomic_fetch_add(cnt, 1u, __ATOMIC_RELAXED, __HIP_MEMORY_SCOPE_AGENT);
            if (!dead) {
                const unsigned int target = 8u * (unsigned int)(t + 1);
                int spins = 0;
                while (__hip_atomic_load(cnt, __ATOMIC_RELAXED, __HIP_MEMORY_SCOPE_AGENT) < target) {
                    __builtin_amdgcn_s_sleep(2);
                    if (++spins > 300000) { dead = true; break; }  // hang -> fast wrong-answer
                }
            }
        }
        __syncthreads();
    }
}

// ---------------- head: out[b] = relu(dot(h_T[b], Wl) + bl) ----------------
__global__ void head_kernel(const __bf16* __restrict__ h, const float* __restrict__ Wl,
                            const float* __restrict__ bl, float* __restrict__ out) {
    const int b = blockIdx.x;
    const int lane = threadIdx.x;  // 64 threads
    const __bf16* hp = h + (size_t)b * Hn;
    float s = 0.f;
    #pragma unroll
    for (int j = lane; j < Hn; j += 64) s += (float)hp[j] * Wl[j];
    #pragma unroll
    for (int off = 32; off > 0; off >>= 1) s += __shfl_down(s, off, 64);
    if (lane == 0) out[b] = fmaxf(s + bl[0], 0.0f);
}

extern "C" void kernel_launch(void* const* d_in, const int* in_sizes, int n_in,
                              void* d_out, int out_size, void* d_ws, size_t ws_size,
                              hipStream_t stream) {
    const float* xd  = (const float*)d_in[0];
    const float* Wih = (const float*)d_in[1];
    const float* Whh = (const float*)d_in[2];
    const float* b   = (const float*)d_in[3];
    const float* Wl  = (const float*)d_in[4];
    const float* bl  = (const float*)d_in[5];
    float* out = (float*)d_out;

    // ws layout:
    //   Wc  bf16 [2048][576] : 2,359,296 B
    //   h0  bf16 [1024][512] : 1,048,576 B
    //   h1  bf16 [1024][512] : 1,048,576 B
    //   bar u32  [32][32]    : 4,096 B
    char* ws = (char*)d_ws;
    __bf16* Wc = (__bf16*)ws;
    __bf16* h0 = (__bf16*)(ws + 2359296);
    __bf16* h1 = (__bf16*)(ws + 2359296 + 1048576);
    unsigned int* bar = (unsigned int*)(ws + 2359296 + 2 * 1048576);

    hipMemsetAsync(h0, 0, 1048576, stream);   // t=0 reads h0 as zeros
    hipMemsetAsync(bar, 0, 4096, stream);     // monotonic barrier counters (32 groups)

    const int total = G4n * Kn;
    convert_weights<<<(total + 255) / 256, 256, 0, stream>>>(Wih, Whh, Wc);

    lstm_persist<<<256, 512, 0, stream>>>(xd, b, Wc, h0, h1, bar);

    // t=729 (odd) writes h0 -> final hidden state is in h0
    head_kernel<<<Bn, 64, 0, stream>>>(h0, Wl, bl, out);
}